// Round 3
// baseline (600.497 us; speedup 1.0000x reference)
//
#include <hip/hip_runtime.h>
#include <stdint.h>
#include <math.h>

#define DIM 1536
#define SEQ 4096
#define HEADS 12
#define HD 128

typedef __bf16 bf16x8 __attribute__((ext_vector_type(8)));
typedef float f32x4 __attribute__((ext_vector_type(4)));

__device__ __forceinline__ float b2f(unsigned short u) {
  union { unsigned int i; float f; } x; x.i = ((unsigned int)u) << 16; return x.f;
}
__device__ __forceinline__ unsigned short f2b(float f) {
  union { float f; unsigned int i; } x; x.f = f;
  unsigned int u = x.i;
  unsigned int r = (u + 0x7fffu + ((u >> 16) & 1u)) >> 16;  // RNE
  return (unsigned short)r;
}
__device__ __forceinline__ float scrub(float v, float sig) {
  return (v == v && v > -3e38f && v < 3e38f) ? v : sig;
}

// ---------------- dtype detector: flag=0 bf16 inputs, flag=1 fp32 inputs
__global__ void detect_kernel(const unsigned int* __restrict__ xw, int* flag) {
  __shared__ int cnt;
  if (threadIdx.x == 0) cnt = 0;
  __syncthreads();
  int local = 0;
  for (int i = threadIdx.x; i < 1024; i += 256) {
    unsigned int e = (xw[i] >> 7) & 0xFFu;
    if (e >= 110u && e <= 140u) local++;
  }
  atomicAdd(&cnt, local);
  __syncthreads();
  if (threadIdx.x == 0) *flag = (cnt > 512) ? 0 : 1;
}

__global__ void convert_bf16_kernel(const void* __restrict__ src,
                                    unsigned short* __restrict__ dst, int n,
                                    const int* __restrict__ flag) {
  int f = *flag;
  for (int i = blockIdx.x * blockDim.x + threadIdx.x; i < n; i += gridDim.x * blockDim.x)
    dst[i] = f ? f2b(((const float*)src)[i]) : ((const unsigned short*)src)[i];
}

__global__ void convert_f32_kernel(const void* __restrict__ src,
                                   float* __restrict__ dst, int n,
                                   const int* __restrict__ flag) {
  int f = *flag;
  for (int i = blockIdx.x * blockDim.x + threadIdx.x; i < n; i += gridDim.x * blockDim.x)
    dst[i] = f ? ((const float*)src)[i] : b2f(((const unsigned short*)src)[i]);
}

__global__ void signal_kernel(float* out) { if (threadIdx.x == 0) out[0] = 999.0f; }

// ---------------- GEMM: C[M,N] = A[M,K] @ W[N,K]^T + bias, bf16 in, fp32 acc
__device__ __forceinline__ void gemm_bt_body(
    const unsigned short* __restrict__ A,
    const unsigned short* __restrict__ W,
    const unsigned short* __restrict__ bias,
    unsigned short* __restrict__ Cb, float* __restrict__ Cf, int fmt,
    int K, int N, int bx, int by)
{
  const int BK = 32, LDK = 40;
  __shared__ unsigned short As[128 * LDK];
  __shared__ unsigned short Bs[128 * LDK];
  const int t = threadIdx.x;
  const int wave = t >> 6, lane = t & 63;
  const int quad = lane >> 4, l16 = lane & 15;
  const int m0 = by * 128, n0 = bx * 128;
  const int wm = (wave >> 1) * 64, wn = (wave & 1) * 64;

  f32x4 acc[4][4] = {};

  const int srow = t >> 1;
  const int scol = (t & 1) * 16;
  const unsigned short* Ag = A + (size_t)(m0 + srow) * K + scol;
  const unsigned short* Wg = W + (size_t)(n0 + srow) * K + scol;
  unsigned short* AsW = &As[srow * LDK + scol];
  unsigned short* BsW = &Bs[srow * LDK + scol];

  for (int k0 = 0; k0 < K; k0 += BK) {
    uint4 a0 = *(const uint4*)(Ag + k0);
    uint4 a1 = *(const uint4*)(Ag + k0 + 8);
    uint4 w0 = *(const uint4*)(Wg + k0);
    uint4 w1 = *(const uint4*)(Wg + k0 + 8);
    __syncthreads();
    *(uint4*)(AsW) = a0; *(uint4*)(AsW + 8) = a1;
    *(uint4*)(BsW) = w0; *(uint4*)(BsW + 8) = w1;
    __syncthreads();
    bf16x8 af[4], bfr[4];
#pragma unroll
    for (int i = 0; i < 4; ++i)
      af[i] = *(const bf16x8*)&As[(wm + i * 16 + l16) * LDK + quad * 8];
#pragma unroll
    for (int j = 0; j < 4; ++j)
      bfr[j] = *(const bf16x8*)&Bs[(wn + j * 16 + l16) * LDK + quad * 8];
#pragma unroll
    for (int i = 0; i < 4; ++i)
#pragma unroll
      for (int j = 0; j < 4; ++j)
        acc[i][j] = __builtin_amdgcn_mfma_f32_16x16x32_bf16(af[i], bfr[j], acc[i][j], 0, 0, 0);
  }

#pragma unroll
  for (int i = 0; i < 4; ++i) {
    int row = m0 + wm + i * 16 + quad * 4;
#pragma unroll
    for (int j = 0; j < 4; ++j) {
      int col = n0 + wn + j * 16 + l16;
      float bv = b2f(bias[col]);
#pragma unroll
      for (int r = 0; r < 4; ++r) {
        float v = scrub(acc[i][j][r] + bv, 12345.0f);
        size_t idx = (size_t)(row + r) * N + col;
        if (fmt) Cf[idx] = v; else Cb[idx] = f2b(v);
      }
    }
  }
}

__global__ __launch_bounds__(256) void qkv_gemm_kernel(
    const unsigned short* __restrict__ x,
    const unsigned short* __restrict__ Wq, const unsigned short* __restrict__ bq,
    const unsigned short* __restrict__ Wk, const unsigned short* __restrict__ bk,
    const unsigned short* __restrict__ Wv, const unsigned short* __restrict__ bv,
    unsigned short* qb, unsigned short* kb, unsigned short* vb)
{
  const unsigned short *W, *b; unsigned short* C;
  if (blockIdx.z == 0)      { W = Wq; b = bq; C = qb; }
  else if (blockIdx.z == 1) { W = Wk; b = bk; C = kb; }
  else                      { W = Wv; b = bv; C = vb; }
  gemm_bt_body(x, W, b, C, nullptr, 0, DIM, DIM, blockIdx.x, blockIdx.y);
}

__global__ __launch_bounds__(256) void out_gemm_kernel(
    const unsigned short* __restrict__ ab, const unsigned short* __restrict__ Wo,
    const unsigned short* __restrict__ bo, void* out, const int* __restrict__ flag)
{
  int fmt = *flag;
  gemm_bt_body(ab, Wo, bo, (unsigned short*)out, (float*)out, fmt,
               DIM, DIM, blockIdx.x, blockIdx.y);
}

// ---------------- RMSNorm + RoPE, in place; freqs in fp32
__global__ __launch_bounds__(256) void norm_rope_kernel(
    unsigned short* __restrict__ qb, unsigned short* __restrict__ kb,
    const unsigned short* __restrict__ gq, const unsigned short* __restrict__ gk,
    const float* __restrict__ freqsf)
{
  const int s = blockIdx.x;
  unsigned short* row = (blockIdx.y == 0 ? qb : kb) + (size_t)s * DIM;
  const unsigned short* g = (blockIdx.y == 0 ? gq : gk);
  const int t = threadIdx.x;
  float ss = 0.f;
#pragma unroll
  for (int i = 0; i < 6; ++i) {
    float xv = b2f(row[t + 256 * i]);
    ss += xv * xv;
  }
#pragma unroll
  for (int off = 32; off > 0; off >>= 1) ss += __shfl_down(ss, off);
  __shared__ float red[4];
  if ((t & 63) == 0) red[t >> 6] = ss;
  __syncthreads();
  float tot = red[0] + red[1] + red[2] + red[3];
  float rinv = 1.0f / sqrtf(tot * (1.0f / DIM) + 1e-6f);
#pragma unroll
  for (int i = 0; i < 3; ++i) {
    int pg = t + 256 * i;
    int c0 = pg * 2;
    float x0 = b2f(row[c0]), x1 = b2f(row[c0 + 1]);
    float y0 = x0 * rinv * b2f(g[c0]);
    float y1 = x1 * rinv * b2f(g[c0 + 1]);
    float ang = freqsf[s * 64 + (pg & 63)];
    float sn, cs;
    __sincosf(ang, &sn, &cs);
    row[c0]     = f2b(y0 * cs - y1 * sn);
    row[c0 + 1] = f2b(y0 * sn + y1 * cs);
  }
}

// ---------------- Flash attention
#define LDKA 136
#define LDV  72
#define LDP  72

__global__ __launch_bounds__(256) void attn_kernel(
    const unsigned short* __restrict__ qb,
    const unsigned short* __restrict__ kb,
    const unsigned short* __restrict__ vb,
    unsigned short* __restrict__ ab)
{
  __shared__ unsigned short Ks[64 * LDKA];
  __shared__ unsigned short Vt[128 * LDV];
  __shared__ unsigned short Ps[4][16 * LDP];

  const int t = threadIdx.x;
  const int wave = t >> 6, lane = t & 63;
  const int quad = lane >> 4, l16 = lane & 15;
  const int h = blockIdx.y;
  const int qbase = blockIdx.x * 64 + wave * 16;
  const float scale = 0.08838834764831845f;

  bf16x8 qf[4];
#pragma unroll
  for (int kk = 0; kk < 4; ++kk)
    qf[kk] = *(const bf16x8*)(qb + (size_t)(qbase + l16) * DIM + h * HD + kk * 32 + quad * 8);

  f32x4 o[8] = {};
  float Mr[4], Lr[4];
#pragma unroll
  for (int r = 0; r < 4; ++r) { Mr[r] = -1e30f; Lr[r] = 0.f; }

  const int krow = t >> 2;
  const int kseg = (t & 3) * 32;
  const int vkey0 = (t & 15) * 4;
  const int vdseg = (t >> 4) * 8;

  for (int kc = 0; kc < SEQ; kc += 64) {
    __syncthreads();
    {
      const unsigned short* src = kb + (size_t)(kc + krow) * DIM + h * HD + kseg;
      uint4 u0 = *(const uint4*)(src);
      uint4 u1 = *(const uint4*)(src + 8);
      uint4 u2 = *(const uint4*)(src + 16);
      uint4 u3 = *(const uint4*)(src + 24);
      unsigned short* dst = &Ks[krow * LDKA + kseg];
      *(uint4*)(dst)      = u0; *(uint4*)(dst + 8)  = u1;
      *(uint4*)(dst + 16) = u2; *(uint4*)(dst + 24) = u3;
    }
    {
      uint4 vr[4];
#pragma unroll
      for (int i = 0; i < 4; ++i)
        vr[i] = *(const uint4*)(vb + (size_t)(kc + vkey0 + i) * DIM + h * HD + vdseg);
#pragma unroll
      for (int j = 0; j < 8; ++j) {
        union { unsigned short h4[4]; uint2 u; } pk;
#pragma unroll
        for (int i = 0; i < 4; ++i) pk.h4[i] = ((const unsigned short*)&vr[i])[j];
        *(uint2*)&Vt[(vdseg + j) * LDV + vkey0] = pk.u;
      }
    }
    __syncthreads();

    f32x4 sc[4] = {};
#pragma unroll
    for (int kk = 0; kk < 4; ++kk) {
#pragma unroll
      for (int j = 0; j < 4; ++j) {
        bf16x8 kf = *(const bf16x8*)&Ks[(j * 16 + l16) * LDKA + kk * 32 + quad * 8];
        sc[j] = __builtin_amdgcn_mfma_f32_16x16x32_bf16(qf[kk], kf, sc[j], 0, 0, 0);
      }
    }
#pragma unroll
    for (int j = 0; j < 4; ++j) sc[j] *= scale;

#pragma unroll
    for (int r = 0; r < 4; ++r) {
      float sm = fmaxf(fmaxf(sc[0][r], sc[1][r]), fmaxf(sc[2][r], sc[3][r]));
#pragma unroll
      for (int off = 1; off < 16; off <<= 1) sm = fmaxf(sm, __shfl_xor(sm, off));
      float newM = fmaxf(Mr[r], sm);
      float alpha = __expf(Mr[r] - newM);
      float ps = 0.f;
#pragma unroll
      for (int j = 0; j < 4; ++j) {
        float p = __expf(sc[j][r] - newM);
        ps += p;
        Ps[wave][(quad * 4 + r) * LDP + j * 16 + l16] = f2b(p);
      }
#pragma unroll
      for (int off = 1; off < 16; off <<= 1) ps += __shfl_xor(ps, off);
      Lr[r] = Lr[r] * alpha + ps;
      Mr[r] = newM;
#pragma unroll
      for (int j2 = 0; j2 < 8; ++j2) o[j2][r] *= alpha;
    }

    __asm__ __volatile__("" ::: "memory");

#pragma unroll
    for (int kk2 = 0; kk2 < 2; ++kk2) {
      bf16x8 pf = *(const bf16x8*)&Ps[wave][l16 * LDP + kk2 * 32 + quad * 8];
#pragma unroll
      for (int j2 = 0; j2 < 8; ++j2) {
        bf16x8 vf = *(const bf16x8*)&Vt[(j2 * 16 + l16) * LDV + kk2 * 32 + quad * 8];
        o[j2] = __builtin_amdgcn_mfma_f32_16x16x32_bf16(pf, vf, o[j2], 0, 0, 0);
      }
    }
  }

  float invl[4];
#pragma unroll
  for (int r = 0; r < 4; ++r) invl[r] = 1.0f / Lr[r];
#pragma unroll
  for (int j2 = 0; j2 < 8; ++j2) {
    int col = h * HD + j2 * 16 + l16;
#pragma unroll
    for (int r = 0; r < 4; ++r) {
      int row = qbase + quad * 4 + r;
      ab[(size_t)row * DIM + col] = f2b(scrub(o[j2][r] * invl[r], 33333.0f));
    }
  }
}

extern "C" void kernel_launch(void* const* d_in, const int* in_sizes, int n_in,
                              void* d_out, int out_size, void* d_ws, size_t ws_size,
                              hipStream_t stream) {
  const int NX = SEQ * DIM, NW = DIM * DIM, NB = DIM, NF = SEQ * 64;

  // ws carve-up (bytes)
  char* w = (char*)d_ws;
  size_t off = 0;
  int* flag = (int*)(w + off);              off += 256;
  unsigned short* xb  = (unsigned short*)(w + off); off += (size_t)NX * 2;
  unsigned short* Wqb = (unsigned short*)(w + off); off += (size_t)NW * 2;
  unsigned short* Wkb = (unsigned short*)(w + off); off += (size_t)NW * 2;
  unsigned short* Wvb = (unsigned short*)(w + off); off += (size_t)NW * 2;
  unsigned short* Wob = (unsigned short*)(w + off); off += (size_t)NW * 2;
  unsigned short* bqb = (unsigned short*)(w + off); off += 4096;
  unsigned short* bkb = (unsigned short*)(w + off); off += 4096;
  unsigned short* bvb = (unsigned short*)(w + off); off += 4096;
  unsigned short* bob = (unsigned short*)(w + off); off += 4096;
  unsigned short* gqb = (unsigned short*)(w + off); off += 4096;
  unsigned short* gkb = (unsigned short*)(w + off); off += 4096;
  float* freqsf = (float*)(w + off);        off += (size_t)NF * 4;
  unsigned short* qb = (unsigned short*)(w + off); off += (size_t)NX * 2;
  unsigned short* kb = (unsigned short*)(w + off); off += (size_t)NX * 2;
  unsigned short* vb = (unsigned short*)(w + off); off += (size_t)NX * 2;
  unsigned short* ab = (unsigned short*)(w + off); off += (size_t)NX * 2;

  if (ws_size < off) {  // ws too small: signal 999 and bail
    signal_kernel<<<1, 64, 0, stream>>>((float*)d_out);
    return;
  }

  detect_kernel<<<1, 256, 0, stream>>>((const unsigned int*)d_in[0], flag);

  const int CT = 256;
  auto cgrid = [](int n) { int g = (n + 255) / 256; return g > 8192 ? 8192 : g; };
  convert_bf16_kernel<<<cgrid(NX), CT, 0, stream>>>(d_in[0], xb,  NX, flag);
  convert_bf16_kernel<<<cgrid(NW), CT, 0, stream>>>(d_in[2], Wqb, NW, flag);
  convert_bf16_kernel<<<cgrid(NW), CT, 0, stream>>>(d_in[4], Wkb, NW, flag);
  convert_bf16_kernel<<<cgrid(NW), CT, 0, stream>>>(d_in[6], Wvb, NW, flag);
  convert_bf16_kernel<<<cgrid(NW), CT, 0, stream>>>(d_in[8], Wob, NW, flag);
  convert_bf16_kernel<<<cgrid(NB), CT, 0, stream>>>(d_in[3], bqb, NB, flag);
  convert_bf16_kernel<<<cgrid(NB), CT, 0, stream>>>(d_in[5], bkb, NB, flag);
  convert_bf16_kernel<<<cgrid(NB), CT, 0, stream>>>(d_in[7], bvb, NB, flag);
  convert_bf16_kernel<<<cgrid(NB), CT, 0, stream>>>(d_in[9], bob, NB, flag);
  convert_bf16_kernel<<<cgrid(NB), CT, 0, stream>>>(d_in[10], gqb, NB, flag);
  convert_bf16_kernel<<<cgrid(NB), CT, 0, stream>>>(d_in[11], gkb, NB, flag);
  convert_f32_kernel<<<cgrid(NF), CT, 0, stream>>>(d_in[1], freqsf, NF, flag);

  qkv_gemm_kernel<<<dim3(DIM / 128, SEQ / 128, 3), 256, 0, stream>>>(
      xb, Wqb, bqb, Wkb, bkb, Wvb, bvb, qb, kb, vb);
  norm_rope_kernel<<<dim3(SEQ, 2), 256, 0, stream>>>(qb, kb, gqb, gkb, freqsf);
  attn_kernel<<<dim3(SEQ / 64, HEADS), 256, 0, stream>>>(qb, kb, vb, ab);
  out_gemm_kernel<<<dim3(DIM / 128, SEQ / 128), 256, 0, stream>>>(ab, Wob, bob, d_out, flag);
}

// Round 4
// 508.604 us; speedup vs baseline: 1.1807x; 1.1807x over previous
//
#include <hip/hip_runtime.h>
#include <stdint.h>
#include <math.h>

#define DIM 1536
#define SEQ 4096
#define HEADS 12
#define HD 128

typedef __bf16 bf16x8 __attribute__((ext_vector_type(8)));
typedef float f32x4 __attribute__((ext_vector_type(4)));

__device__ __forceinline__ float b2f(unsigned short u) {
  union { unsigned int i; float f; } x; x.i = ((unsigned int)u) << 16; return x.f;
}
__device__ __forceinline__ unsigned short f2b(float f) {
  union { float f; unsigned int i; } x; x.f = f;
  unsigned int u = x.i;
  unsigned int r = (u + 0x7fffu + ((u >> 16) & 1u)) >> 16;  // RNE
  return (unsigned short)r;
}

// ---------------- dtype detector: flag=0 bf16 inputs, flag=1 fp32 inputs
__global__ void detect_kernel(const unsigned int* __restrict__ xw, int* flag) {
  __shared__ int cnt;
  if (threadIdx.x == 0) cnt = 0;
  __syncthreads();
  int local = 0;
  for (int i = threadIdx.x; i < 1024; i += 256) {
    unsigned int e = (xw[i] >> 7) & 0xFFu;
    if (e >= 110u && e <= 140u) local++;
  }
  atomicAdd(&cnt, local);
  __syncthreads();
  if (threadIdx.x == 0) *flag = (cnt > 512) ? 0 : 1;
}

__global__ void convert_bf16_kernel(const void* __restrict__ src,
                                    unsigned short* __restrict__ dst, int n,
                                    const int* __restrict__ flag) {
  int f = *flag;
  for (int i = blockIdx.x * blockDim.x + threadIdx.x; i < n; i += gridDim.x * blockDim.x)
    dst[i] = f ? f2b(((const float*)src)[i]) : ((const unsigned short*)src)[i];
}

__global__ void convert_f32_kernel(const void* __restrict__ src,
                                   float* __restrict__ dst, int n,
                                   const int* __restrict__ flag) {
  int f = *flag;
  for (int i = blockIdx.x * blockDim.x + threadIdx.x; i < n; i += gridDim.x * blockDim.x)
    dst[i] = f ? ((const float*)src)[i] : b2f(((const unsigned short*)src)[i]);
}

__global__ void signal_kernel(float* out) { if (threadIdx.x == 0) out[0] = 999.0f; }

// ---------------- GEMM: C[M,N] = A[M,K] @ W[N,K]^T + bias, bf16 in, fp32 acc
// vmode=1: write transposed vt[col][row] (V projection), packed 4 rows/uint2
__device__ __forceinline__ void gemm_bt_body(
    const unsigned short* __restrict__ A,
    const unsigned short* __restrict__ W,
    const unsigned short* __restrict__ bias,
    unsigned short* __restrict__ Cb, float* __restrict__ Cf, int fmt, int vmode,
    int K, int N, int bx, int by)
{
  const int BK = 32, LDK = 40;
  __shared__ unsigned short As[128 * LDK];
  __shared__ unsigned short Bs[128 * LDK];
  const int t = threadIdx.x;
  const int wave = t >> 6, lane = t & 63;
  const int quad = lane >> 4, l16 = lane & 15;
  const int m0 = by * 128, n0 = bx * 128;
  const int wm = (wave >> 1) * 64, wn = (wave & 1) * 64;

  f32x4 acc[4][4] = {};

  const int srow = t >> 1;
  const int scol = (t & 1) * 16;
  const unsigned short* Ag = A + (size_t)(m0 + srow) * K + scol;
  const unsigned short* Wg = W + (size_t)(n0 + srow) * K + scol;
  unsigned short* AsW = &As[srow * LDK + scol];
  unsigned short* BsW = &Bs[srow * LDK + scol];

  for (int k0 = 0; k0 < K; k0 += BK) {
    uint4 a0 = *(const uint4*)(Ag + k0);
    uint4 a1 = *(const uint4*)(Ag + k0 + 8);
    uint4 w0 = *(const uint4*)(Wg + k0);
    uint4 w1 = *(const uint4*)(Wg + k0 + 8);
    __syncthreads();
    *(uint4*)(AsW) = a0; *(uint4*)(AsW + 8) = a1;
    *(uint4*)(BsW) = w0; *(uint4*)(BsW + 8) = w1;
    __syncthreads();
    bf16x8 af[4], bfr[4];
#pragma unroll
    for (int i = 0; i < 4; ++i)
      af[i] = *(const bf16x8*)&As[(wm + i * 16 + l16) * LDK + quad * 8];
#pragma unroll
    for (int j = 0; j < 4; ++j)
      bfr[j] = *(const bf16x8*)&Bs[(wn + j * 16 + l16) * LDK + quad * 8];
#pragma unroll
    for (int i = 0; i < 4; ++i)
#pragma unroll
      for (int j = 0; j < 4; ++j)
        acc[i][j] = __builtin_amdgcn_mfma_f32_16x16x32_bf16(af[i], bfr[j], acc[i][j], 0, 0, 0);
  }

#pragma unroll
  for (int i = 0; i < 4; ++i) {
    int row = m0 + wm + i * 16 + quad * 4;
#pragma unroll
    for (int j = 0; j < 4; ++j) {
      int col = n0 + wn + j * 16 + l16;
      float bv = b2f(bias[col]);
      if (vmode) {  // transposed: vt[col][row..row+3], 8B packed store
        union { unsigned short h4[4]; uint2 u; } pk;
#pragma unroll
        for (int r = 0; r < 4; ++r) pk.h4[r] = f2b(acc[i][j][r] + bv);
        *(uint2*)&Cb[(size_t)col * SEQ + row] = pk.u;
      } else {
#pragma unroll
        for (int r = 0; r < 4; ++r) {
          float v = acc[i][j][r] + bv;
          size_t idx = (size_t)(row + r) * N + col;
          if (fmt) Cf[idx] = v; else Cb[idx] = f2b(v);
        }
      }
    }
  }
}

__global__ __launch_bounds__(256) void qkv_gemm_kernel(
    const unsigned short* __restrict__ x,
    const unsigned short* __restrict__ Wq, const unsigned short* __restrict__ bq,
    const unsigned short* __restrict__ Wk, const unsigned short* __restrict__ bk,
    const unsigned short* __restrict__ Wv, const unsigned short* __restrict__ bv,
    unsigned short* qb, unsigned short* kb, unsigned short* vt)
{
  const unsigned short *W, *b; unsigned short* C; int vm = 0;
  if (blockIdx.z == 0)      { W = Wq; b = bq; C = qb; }
  else if (blockIdx.z == 1) { W = Wk; b = bk; C = kb; }
  else                      { W = Wv; b = bv; C = vt; vm = 1; }
  gemm_bt_body(x, W, b, C, nullptr, 0, vm, DIM, DIM, blockIdx.x, blockIdx.y);
}

__global__ __launch_bounds__(256) void out_gemm_kernel(
    const unsigned short* __restrict__ ab, const unsigned short* __restrict__ Wo,
    const unsigned short* __restrict__ bo, void* out, const int* __restrict__ flag)
{
  int fmt = *flag;
  gemm_bt_body(ab, Wo, bo, (unsigned short*)out, (float*)out, fmt, 0,
               DIM, DIM, blockIdx.x, blockIdx.y);
}

// ---------------- RMSNorm + RoPE, in place; q additionally pre-scaled 1/sqrt(d)
__global__ __launch_bounds__(256) void norm_rope_kernel(
    unsigned short* __restrict__ qb, unsigned short* __restrict__ kb,
    const unsigned short* __restrict__ gq, const unsigned short* __restrict__ gk,
    const float* __restrict__ freqsf)
{
  const int s = blockIdx.x;
  const int isq = (blockIdx.y == 0);
  unsigned short* row = (isq ? qb : kb) + (size_t)s * DIM;
  const unsigned short* g = (isq ? gq : gk);
  const int t = threadIdx.x;
  float ss = 0.f;
#pragma unroll
  for (int i = 0; i < 6; ++i) {
    float xv = b2f(row[t + 256 * i]);
    ss += xv * xv;
  }
#pragma unroll
  for (int off = 32; off > 0; off >>= 1) ss += __shfl_down(ss, off);
  __shared__ float red[4];
  if ((t & 63) == 0) red[t >> 6] = ss;
  __syncthreads();
  float tot = red[0] + red[1] + red[2] + red[3];
  float rinv = 1.0f / sqrtf(tot * (1.0f / DIM) + 1e-6f);
  if (isq) rinv *= 0.08838834764831845f;   // fold 1/sqrt(128) into q
#pragma unroll
  for (int i = 0; i < 3; ++i) {
    int pg = t + 256 * i;
    int c0 = pg * 2;
    float x0 = b2f(row[c0]), x1 = b2f(row[c0 + 1]);
    float y0 = x0 * rinv * b2f(g[c0]);
    float y1 = x1 * rinv * b2f(g[c0 + 1]);
    float ang = freqsf[s * 64 + (pg & 63)];
    float sn, cs;
    __sincosf(ang, &sn, &cs);
    row[c0]     = f2b(y0 * cs - y1 * sn);
    row[c0 + 1] = f2b(y0 * sn + y1 * cs);
  }
}

// ---------------- Flash attention, fixed-max softmax (scores bounded ~12)
#define LDKA 136
#define LDV  72
#define LDP  72

__global__ __launch_bounds__(256) void attn_kernel(
    const unsigned short* __restrict__ qb,
    const unsigned short* __restrict__ kb,
    const unsigned short* __restrict__ vt,   // [DIM col][SEQ] transposed V
    unsigned short* __restrict__ ab)
{
  __shared__ unsigned short Ks[64 * LDKA];
  __shared__ unsigned short Vs[128 * LDV];     // [d][key]
  __shared__ __bf16 Ps[4][16 * LDP];

  const int t = threadIdx.x;
  const int wave = t >> 6, lane = t & 63;
  const int quad = lane >> 4, l16 = lane & 15;
  const int h = blockIdx.y;
  const int qbase = blockIdx.x * 64 + wave * 16;

  bf16x8 qf[4];
#pragma unroll
  for (int kk = 0; kk < 4; ++kk)
    qf[kk] = *(const bf16x8*)(qb + (size_t)(qbase + l16) * DIM + h * HD + kk * 32 + quad * 8);

  f32x4 o[8] = {};
  float Lr[4] = {0.f, 0.f, 0.f, 0.f};   // per-lane partial sums (reduced at end)

  const int krow = t >> 2;             // K staging: 4 threads per key row
  const int kseg = (t & 3) * 32;
  const int vd   = t >> 1;             // V staging: 2 threads per d row
  const int vks  = (t & 1) * 32;

  for (int kc = 0; kc < SEQ; kc += 64) {
    __syncthreads();
    {  // stage K [64][128]
      const unsigned short* src = kb + (size_t)(kc + krow) * DIM + h * HD + kseg;
      uint4 u0 = *(const uint4*)(src);
      uint4 u1 = *(const uint4*)(src + 8);
      uint4 u2 = *(const uint4*)(src + 16);
      uint4 u3 = *(const uint4*)(src + 24);
      unsigned short* dst = &Ks[krow * LDKA + kseg];
      *(uint4*)(dst)      = u0; *(uint4*)(dst + 8)  = u1;
      *(uint4*)(dst + 16) = u2; *(uint4*)(dst + 24) = u3;
    }
    {  // stage V from pre-transposed vt: pure b128 copies, no repack
      const unsigned short* src = vt + ((size_t)h * HD + vd) * SEQ + kc + vks;
      uint4 u0 = *(const uint4*)(src);
      uint4 u1 = *(const uint4*)(src + 8);
      uint4 u2 = *(const uint4*)(src + 16);
      uint4 u3 = *(const uint4*)(src + 24);
      unsigned short* dst = &Vs[vd * LDV + vks];
      *(uint4*)(dst)      = u0; *(uint4*)(dst + 8)  = u1;
      *(uint4*)(dst + 16) = u2; *(uint4*)(dst + 24) = u3;
    }
    __syncthreads();

    // S = Q @ K^T (Q pre-scaled by 1/sqrt(d))
    f32x4 sc[4] = {};
#pragma unroll
    for (int kk = 0; kk < 4; ++kk) {
#pragma unroll
      for (int j = 0; j < 4; ++j) {
        bf16x8 kf = *(const bf16x8*)&Ks[(j * 16 + l16) * LDKA + kk * 32 + quad * 8];
        sc[j] = __builtin_amdgcn_mfma_f32_16x16x32_bf16(qf[kk], kf, sc[j], 0, 0, 0);
      }
    }

    // fixed-max softmax: P = exp(s), per-lane L accumulation, no rescale
#pragma unroll
    for (int j = 0; j < 4; ++j) {
#pragma unroll
      for (int r = 0; r < 4; ++r) {
        float p = __expf(sc[j][r]);
        Lr[r] += p;
        Ps[wave][(quad * 4 + r) * LDP + j * 16 + l16] = (__bf16)p;
      }
    }

    __asm__ __volatile__("" ::: "memory");

    // O += P @ V
#pragma unroll
    for (int kk2 = 0; kk2 < 2; ++kk2) {
      bf16x8 pf = *(const bf16x8*)&Ps[wave][l16 * LDP + kk2 * 32 + quad * 8];
#pragma unroll
      for (int j2 = 0; j2 < 8; ++j2) {
        bf16x8 vf = *(const bf16x8*)&Vs[(j2 * 16 + l16) * LDV + kk2 * 32 + quad * 8];
        o[j2] = __builtin_amdgcn_mfma_f32_16x16x32_bf16(pf, vf, o[j2], 0, 0, 0);
      }
    }
  }

  // reduce Lr across the 16 lanes (same quad) holding disjoint keys of a row
  float invl[4];
#pragma unroll
  for (int r = 0; r < 4; ++r) {
    float L = Lr[r];
#pragma unroll
    for (int off = 1; off < 16; off <<= 1) L += __shfl_xor(L, off);
    invl[r] = 1.0f / L;
  }
#pragma unroll
  for (int j2 = 0; j2 < 8; ++j2) {
    int col = h * HD + j2 * 16 + l16;
#pragma unroll
    for (int r = 0; r < 4; ++r) {
      int row = qbase + quad * 4 + r;
      ab[(size_t)row * DIM + col] = f2b(o[j2][r] * invl[r]);
    }
  }
}

extern "C" void kernel_launch(void* const* d_in, const int* in_sizes, int n_in,
                              void* d_out, int out_size, void* d_ws, size_t ws_size,
                              hipStream_t stream) {
  const int NX = SEQ * DIM, NW = DIM * DIM, NB = DIM, NF = SEQ * 64;

  char* w = (char*)d_ws;
  size_t off = 0;
  int* flag = (int*)(w + off);              off += 256;
  unsigned short* xb  = (unsigned short*)(w + off); off += (size_t)NX * 2;
  unsigned short* Wqb = (unsigned short*)(w + off); off += (size_t)NW * 2;
  unsigned short* Wkb = (unsigned short*)(w + off); off += (size_t)NW * 2;
  unsigned short* Wvb = (unsigned short*)(w + off); off += (size_t)NW * 2;
  unsigned short* Wob = (unsigned short*)(w + off); off += (size_t)NW * 2;
  unsigned short* bqb = (unsigned short*)(w + off); off += 4096;
  unsigned short* bkb = (unsigned short*)(w + off); off += 4096;
  unsigned short* bvb = (unsigned short*)(w + off); off += 4096;
  unsigned short* bob = (unsigned short*)(w + off); off += 4096;
  unsigned short* gqb = (unsigned short*)(w + off); off += 4096;
  unsigned short* gkb = (unsigned short*)(w + off); off += 4096;
  float* freqsf = (float*)(w + off);        off += (size_t)NF * 4;
  unsigned short* qb = (unsigned short*)(w + off); off += (size_t)NX * 2;
  unsigned short* kb = (unsigned short*)(w + off); off += (size_t)NX * 2;
  unsigned short* vt = (unsigned short*)(w + off); off += (size_t)NX * 2;
  unsigned short* ab = (unsigned short*)(w + off); off += (size_t)NX * 2;

  if (ws_size < off) {
    signal_kernel<<<1, 64, 0, stream>>>((float*)d_out);
    return;
  }

  detect_kernel<<<1, 256, 0, stream>>>((const unsigned int*)d_in[0], flag);

  const int CT = 256;
  auto cgrid = [](int n) { int g = (n + 255) / 256; return g > 8192 ? 8192 : g; };
  convert_bf16_kernel<<<cgrid(NX), CT, 0, stream>>>(d_in[0], xb,  NX, flag);
  convert_bf16_kernel<<<cgrid(NW), CT, 0, stream>>>(d_in[2], Wqb, NW, flag);
  convert_bf16_kernel<<<cgrid(NW), CT, 0, stream>>>(d_in[4], Wkb, NW, flag);
  convert_bf16_kernel<<<cgrid(NW), CT, 0, stream>>>(d_in[6], Wvb, NW, flag);
  convert_bf16_kernel<<<cgrid(NW), CT, 0, stream>>>(d_in[8], Wob, NW, flag);
  convert_bf16_kernel<<<cgrid(NB), CT, 0, stream>>>(d_in[3], bqb, NB, flag);
  convert_bf16_kernel<<<cgrid(NB), CT, 0, stream>>>(d_in[5], bkb, NB, flag);
  convert_bf16_kernel<<<cgrid(NB), CT, 0, stream>>>(d_in[7], bvb, NB, flag);
  convert_bf16_kernel<<<cgrid(NB), CT, 0, stream>>>(d_in[9], bob, NB, flag);
  convert_bf16_kernel<<<cgrid(NB), CT, 0, stream>>>(d_in[10], gqb, NB, flag);
  convert_bf16_kernel<<<cgrid(NB), CT, 0, stream>>>(d_in[11], gkb, NB, flag);
  convert_f32_kernel<<<cgrid(NF), CT, 0, stream>>>(d_in[1], freqsf, NF, flag);

  qkv_gemm_kernel<<<dim3(DIM / 128, SEQ / 128, 3), 256, 0, stream>>>(
      xb, Wqb, bqb, Wkb, bkb, Wvb, bvb, qb, kb, vt);
  norm_rope_kernel<<<dim3(SEQ, 2), 256, 0, stream>>>(qb, kb, gqb, gkb, freqsf);
  attn_kernel<<<dim3(SEQ / 64, HEADS), 256, 0, stream>>>(qb, kb, vt, ab);
  out_gemm_kernel<<<dim3(DIM / 128, SEQ / 128), 256, 0, stream>>>(ab, Wob, bob, d_out, flag);
}